// Round 2
// baseline (524.719 us; speedup 1.0000x reference)
//
#include <hip/hip_runtime.h>
#include <hip/hip_bf16.h>

#define NTOT 262144  // 64*64*64 spatial
typedef __hip_bfloat16 bf16;
typedef __attribute__((ext_vector_type(8))) short short8;
typedef __attribute__((ext_vector_type(4))) float f32x4;

__device__ inline ushort f2bf(float f){ bf16 b = __float2bfloat16(f); return *(ushort*)&b; }
__device__ inline float bf2f(ushort u){ union{unsigned i;float f;}v; v.i = (unsigned)u<<16; return v.f; }

// ---- dtype detector: flag=1 if inputs are bf16, 0 if fp32 ----
// Looks at the LOW ushort of the first 512 32-bit words of w_qkv.
// bf16 data: that ushort is a real bf16 value (exponent near 127 or zero).
// fp32 data: that ushort is low mantissa bits (exponent field ~uniform junk).
__global__ void detect_dtype(const ushort* __restrict__ w, int* __restrict__ flag) {
  int tid = threadIdx.x;  // 64 threads
  int sane = 0;
  for (int i = tid; i < 512; i += 64) {
    ushort u = w[2 * i];
    int e = (u >> 7) & 0xff;
    sane += (e == 0 || (e >= 100 && e <= 140)) ? 1 : 0;
  }
#pragma unroll
  for (int off = 32; off > 0; off >>= 1) sane += __shfl_down(sane, off, 64);
  if (tid == 0) *flag = (sane >= 256) ? 1 : 0;
}

// convert a small array to internal bf16 (identity if already bf16)
__global__ void cvt_bf16(const void* __restrict__ in, ushort* __restrict__ outw,
                         int n, const int* __restrict__ flag) {
  int f = *flag;
  for (int i = blockIdx.x * 256 + threadIdx.x; i < n; i += gridDim.x * 256)
    outw[i] = f ? ((const ushort*)in)[i] : f2bf(((const float*)in)[i]);
}

// C[o][n] = sum_c W[o][c] * X[c][n], K=96, O = 96*OF
// block: 384 threads = 6 waves; n-tile = 64; wave w covers o rows [w*16*OF, +16*OF)
template<int OF, bool DYNIN, bool DYNOUT>
__global__ __launch_bounds__(384)
void gemm96(const ushort* __restrict__ W, const void* __restrict__ X,
            void* __restrict__ C, const int* __restrict__ flag) {
  __shared__ __align__(16) ushort xs[64][104];
  const int tid = threadIdx.x;
  const long n0 = (long)blockIdx.x * 64;
  const int f = *flag;
  {
    int c = tid % 96, nq = tid / 96;  // nq in 0..3
    ushort tmp[16];
    if (!DYNIN || f) {  // bf16 source
      const ushort* xp = (const ushort*)X + (size_t)c * NTOT + n0 + nq * 16;
      uint4 a0 = *(const uint4*)xp;
      uint4 a1 = *(const uint4*)(xp + 8);
      const unsigned* aw = (const unsigned*)&a0;
#pragma unroll
      for (int i = 0; i < 4; i++) { tmp[2*i] = (ushort)(aw[i] & 0xffffu); tmp[2*i+1] = (ushort)(aw[i] >> 16); }
      const unsigned* aw1 = (const unsigned*)&a1;
#pragma unroll
      for (int i = 0; i < 4; i++) { tmp[8+2*i] = (ushort)(aw1[i] & 0xffffu); tmp[8+2*i+1] = (ushort)(aw1[i] >> 16); }
    } else {            // fp32 source -> round to bf16
      const float* xp = (const float*)X + (size_t)c * NTOT + n0 + nq * 16;
#pragma unroll
      for (int k = 0; k < 4; k++) {
        float4 v = *(const float4*)(xp + 4 * k);
        tmp[4*k+0] = f2bf(v.x); tmp[4*k+1] = f2bf(v.y);
        tmp[4*k+2] = f2bf(v.z); tmp[4*k+3] = f2bf(v.w);
      }
    }
    ushort* dst = &xs[nq * 16][c];
#pragma unroll
    for (int i = 0; i < 16; i++) dst[i * 104] = tmp[i];
  }
  __syncthreads();
  const int wave = tid >> 6, lane = tid & 63;
  const int col = lane & 15, quad = lane >> 4;
  f32x4 acc[OF][4];
#pragma unroll
  for (int a = 0; a < OF; a++)
#pragma unroll
    for (int b = 0; b < 4; b++) acc[a][b] = (f32x4)0.f;
  const int obase = wave * (16 * OF);
#pragma unroll
  for (int ks = 0; ks < 3; ks++) {
    short8 bfrag[4];
#pragma unroll
    for (int nf = 0; nf < 4; nf++)
      bfrag[nf] = *(const short8*)&xs[nf*16 + col][ks*32 + quad*8];
#pragma unroll
    for (int of = 0; of < OF; of++) {
      const int o = obase + of*16 + col;  // A-row = lane&15
      short8 afrag = *(const short8*)(W + (size_t)o * 96 + ks*32 + quad*8);
#pragma unroll
      for (int nf = 0; nf < 4; nf++)
        acc[of][nf] = __builtin_amdgcn_mfma_f32_16x16x32_bf16(afrag, bfrag[nf], acc[of][nf], 0, 0, 0);
    }
  }
  // C/D layout: col = lane&15 (n), row = quad*4 + r (o)
#pragma unroll
  for (int of = 0; of < OF; of++)
#pragma unroll
    for (int nf = 0; nf < 4; nf++)
#pragma unroll
      for (int r = 0; r < 4; r++) {
        int o = obase + of*16 + quad*4 + r;
        long n = n0 + nf*16 + col;
        float v = acc[of][nf][r];
        if (!DYNOUT || f) ((ushort*)C)[(size_t)o * NTOT + n] = f2bf(v);
        else              ((float*) C)[(size_t)o * NTOT + n] = v;
      }
}

// depthwise 3x3x3, pad 1. block 256: dq(8) x wl(8) x hl(4); each thread does 8 d-outputs
__global__ __launch_bounds__(256)
void dwconv3(const ushort* __restrict__ in, const void* __restrict__ wt,
             ushort* __restrict__ out, const int* __restrict__ flag) {
  const int c = blockIdx.z;
  const int tid = threadIdx.x;
  const int dq = tid & 7;
  const int w = blockIdx.y * 8 + ((tid >> 3) & 7);
  const int h = blockIdx.x * 4 + (tid >> 6);
  const int d0 = dq * 8;
  __shared__ float wsm[27];
  if (tid < 27) {
    int f = *flag;
    wsm[tid] = f ? bf2f(((const ushort*)wt)[c * 27 + tid])
                 : ((const float*)wt)[c * 27 + tid];
  }
  __syncthreads();
  float acc[8];
#pragma unroll
  for (int i = 0; i < 8; i++) acc[i] = 0.f;
  const size_t cbase = (size_t)c * NTOT;
#pragma unroll
  for (int dh = -1; dh <= 1; dh++) {
    int hh = h + dh;
    if (hh < 0 || hh > 63) continue;
#pragma unroll
    for (int dw = -1; dw <= 1; dw++) {
      int ww = w + dw;
      if (ww < 0 || ww > 63) continue;
      const ushort* p = in + cbase + ((size_t)hh * 64 + ww) * 64 + d0;
      uint4 va = *(const uint4*)p;
      const unsigned* u = (const unsigned*)&va;
      float x0 = bf2f((ushort)(u[0] & 0xffffu)), x1 = bf2f((ushort)(u[0] >> 16));
      float x2 = bf2f((ushort)(u[1] & 0xffffu)), x3 = bf2f((ushort)(u[1] >> 16));
      float x4 = bf2f((ushort)(u[2] & 0xffffu)), x5 = bf2f((ushort)(u[2] >> 16));
      float x6 = bf2f((ushort)(u[3] & 0xffffu)), x7 = bf2f((ushort)(u[3] >> 16));
      float xl = (d0 > 0)  ? bf2f(p[-1]) : 0.f;
      float xr = (d0 < 56) ? bf2f(p[8])  : 0.f;
      const int wb = (dh + 1) * 9 + (dw + 1) * 3;
      float wL = wsm[wb], wC = wsm[wb + 1], wR = wsm[wb + 2];
      acc[0] += wL*xl + wC*x0 + wR*x1;
      acc[1] += wL*x0 + wC*x1 + wR*x2;
      acc[2] += wL*x1 + wC*x2 + wR*x3;
      acc[3] += wL*x2 + wC*x3 + wR*x4;
      acc[4] += wL*x3 + wC*x4 + wR*x5;
      acc[5] += wL*x4 + wC*x5 + wR*x6;
      acc[6] += wL*x5 + wC*x6 + wR*x7;
      acc[7] += wL*x6 + wC*x7 + wR*xr;
    }
  }
  ushort o8[8];
#pragma unroll
  for (int i = 0; i < 8; i++) o8[i] = f2bf(acc[i]);
  *(uint4*)(out + cbase + ((size_t)h * 64 + w) * 64 + d0) = *(uint4*)o8;
}

// per-head Gram: G[hd][0]=q.kT, [1]=q.qT, [2]=k.kT  (each 16x16 fp32, atomic accum)
__global__ __launch_bounds__(256)
void gram16(const ushort* __restrict__ qk, float* __restrict__ G) {
  const int hd = blockIdx.y;
  const int tid = threadIdx.x, wave = tid >> 6, lane = tid & 63;
  const int col = lane & 15, quad = lane >> 4;
  const ushort* qp = qk + (size_t)(hd * 16 + col) * NTOT;
  const ushort* kp = qp + (size_t)96 * NTOT;
  f32x4 aqk = (f32x4)0.f, aqq = (f32x4)0.f, akk = (f32x4)0.f;
  const int nbase = blockIdx.x * 4096 + wave * 32 + quad * 8;
#pragma unroll 4
  for (int it = 0; it < 32; it++) {
    short8 qf = *(const short8*)(qp + nbase + it * 128);
    short8 kf = *(const short8*)(kp + nbase + it * 128);
    aqk = __builtin_amdgcn_mfma_f32_16x16x32_bf16(qf, kf, aqk, 0, 0, 0);
    aqq = __builtin_amdgcn_mfma_f32_16x16x32_bf16(qf, qf, aqq, 0, 0, 0);
    akk = __builtin_amdgcn_mfma_f32_16x16x32_bf16(kf, kf, akk, 0, 0, 0);
  }
  __shared__ float red[4][64][12];
#pragma unroll
  for (int r = 0; r < 4; r++) {
    red[wave][lane][r]     = aqk[r];
    red[wave][lane][4 + r] = aqq[r];
    red[wave][lane][8 + r] = akk[r];
  }
  __syncthreads();
  if (wave == 0) {
#pragma unroll
    for (int j = 0; j < 12; j++) {
      float v = red[0][lane][j] + red[1][lane][j] + red[2][lane][j] + red[3][lane][j];
      int sub = j >> 2, r = j & 3;
      atomicAdd(&G[hd * 768 + sub * 256 + (quad * 4 + r) * 16 + col], v);
    }
  }
}

// softmax over Gram + fold W_proj: M[o][hd*16+d] = sum_c wp[o][hd*16+c] * A[hd][c][d]
__global__ __launch_bounds__(256)
void attn_mix(const float* __restrict__ G, const void* __restrict__ wp,
              const void* __restrict__ temp, ushort* __restrict__ M,
              const int* __restrict__ flag) {
  __shared__ float As[6][16][16];
  const int tid = threadIdx.x;
  const int f = *flag;
  if (tid < 96) {
    int hd = tid >> 4, c = tid & 15;
    const float* Gh = G + hd * 768;
    float qn = fmaxf(sqrtf(fmaxf(Gh[256 + c * 17], 0.f)), 1e-12f);
    float t = f ? bf2f(((const ushort*)temp)[hd]) : ((const float*)temp)[hd];
    float lg[16];
    float mx = -1e30f;
#pragma unroll
    for (int d = 0; d < 16; d++) {
      float kn = fmaxf(sqrtf(fmaxf(Gh[512 + d * 17], 0.f)), 1e-12f);
      lg[d] = Gh[c * 16 + d] / (qn * kn) * t;
      mx = fmaxf(mx, lg[d]);
    }
    float s = 0.f;
#pragma unroll
    for (int d = 0; d < 16; d++) { lg[d] = __expf(lg[d] - mx); s += lg[d]; }
    float inv = 1.f / s;
#pragma unroll
    for (int d = 0; d < 16; d++) As[hd][c][d] = lg[d] * inv;
  }
  __syncthreads();
  for (int i = 0; i < 36; i++) {
    int idx = tid + 256 * i;           // 0..9215 covers 96*96
    int o = idx / 96, p = idx - o * 96;
    int hd = p >> 4, d = p & 15;
    float s = 0.f;
#pragma unroll
    for (int cc = 0; cc < 16; cc++) {
      float wv = f ? bf2f(((const ushort*)wp)[o * 96 + hd * 16 + cc])
                   : ((const float*)wp)[o * 96 + hd * 16 + cc];
      s += wv * As[hd][cc][d];
    }
    M[idx] = f2bf(s);
  }
}

extern "C" void kernel_launch(void* const* d_in, const int* in_sizes, int n_in,
                              void* d_out, int out_size, void* d_ws, size_t ws_size,
                              hipStream_t stream) {
  const void* x      = d_in[0];  // (96, 64,64,64)
  const void* w_qkv  = d_in[1];  // (288, 96)
  const void* w_dw   = d_in[2];  // (288, 27)
  const void* w_proj = d_in[3];  // (96, 96)
  const void* temp   = d_in[4];  // (6)

  const size_t szQKV = (size_t)288 * NTOT * 2;  // 151 MB
  ushort* B1 = (ushort*)d_ws;                                      // qkv after 1x1
  ushort* B2 = (ushort*)((char*)d_ws + szQKV);                     // qkv after dwconv
  char* tail = (char*)d_ws + 2 * szQKV;
  float*  G    = (float*)tail;                    // 6*768 fp32      (18432 B)
  ushort* M    = (ushort*)(tail + 18432);         // 96*96 bf16      (18432 B)
  ushort* Wb   = (ushort*)(tail + 36864);         // 288*96 bf16     (55296 B)
  int*    flag = (int*)(tail + 92160);
  if (ws_size < 2 * szQKV + 92160 + 256) return;  // fail loudly (zeros out)

  detect_dtype<<<1, 64, 0, stream>>>((const ushort*)w_qkv, flag);
  cvt_bf16<<<32, 256, 0, stream>>>(w_qkv, Wb, 288 * 96, flag);
  hipMemsetAsync(G, 0, 4608 * 4, stream);
  gemm96<3, true, false><<<4096, 384, 0, stream>>>(Wb, x, B1, flag);
  dwconv3<<<dim3(16, 8, 288), 256, 0, stream>>>(B1, w_dw, B2, flag);
  gram16<<<dim3(64, 6), 256, 0, stream>>>(B2, G);
  attn_mix<<<1, 256, 0, stream>>>(G, w_proj, temp, M, flag);
  gemm96<1, false, true><<<4096, 384, 0, stream>>>(M, B2 + (size_t)192 * NTOT, d_out, flag);
}

// Round 3
// 450.813 us; speedup vs baseline: 1.1639x; 1.1639x over previous
//
#include <hip/hip_runtime.h>
#include <hip/hip_bf16.h>

#define NTOT 262144  // 64*64*64 spatial
typedef __hip_bfloat16 bf16;
typedef __attribute__((ext_vector_type(8))) short short8;
typedef __attribute__((ext_vector_type(4))) float f32x4;

__device__ inline ushort f2bf(float f){ bf16 b = __float2bfloat16(f); return *(ushort*)&b; }
__device__ inline float bf2f(ushort u){ union{unsigned i;float f;}v; v.i = (unsigned)u<<16; return v.f; }

// ---- dtype detector: flag=1 if inputs are bf16, 0 if fp32 ----
__global__ void detect_dtype(const ushort* __restrict__ w, int* __restrict__ flag) {
  int tid = threadIdx.x;  // 64 threads
  int sane = 0;
  for (int i = tid; i < 512; i += 64) {
    ushort u = w[2 * i];
    int e = (u >> 7) & 0xff;
    sane += (e == 0 || (e >= 100 && e <= 140)) ? 1 : 0;
  }
#pragma unroll
  for (int off = 32; off > 0; off >>= 1) sane += __shfl_down(sane, off, 64);
  if (tid == 0) *flag = (sane >= 256) ? 1 : 0;
}

// convert a small array to internal bf16 (identity if already bf16)
__global__ void cvt_bf16(const void* __restrict__ in, ushort* __restrict__ outw,
                         int n, const int* __restrict__ flag) {
  int f = *flag;
  for (int i = blockIdx.x * 256 + threadIdx.x; i < n; i += gridDim.x * 256)
    outw[i] = f ? ((const ushort*)in)[i] : f2bf(((const float*)in)[i]);
}

// C[o][n] = sum_c W[o][c] * X[c][n], K=96, O = 96*OF
template<int OF, bool DYNIN, bool DYNOUT>
__global__ __launch_bounds__(384)
void gemm96(const ushort* __restrict__ W, const void* __restrict__ X,
            void* __restrict__ C, const int* __restrict__ flag) {
  __shared__ __align__(16) ushort xs[64][104];
  const int tid = threadIdx.x;
  const long n0 = (long)blockIdx.x * 64;
  const int f = *flag;
  {
    int c = tid % 96, nq = tid / 96;  // nq in 0..3
    ushort tmp[16];
    if (!DYNIN || f) {  // bf16 source
      const ushort* xp = (const ushort*)X + (size_t)c * NTOT + n0 + nq * 16;
      uint4 a0 = *(const uint4*)xp;
      uint4 a1 = *(const uint4*)(xp + 8);
      const unsigned* aw = (const unsigned*)&a0;
#pragma unroll
      for (int i = 0; i < 4; i++) { tmp[2*i] = (ushort)(aw[i] & 0xffffu); tmp[2*i+1] = (ushort)(aw[i] >> 16); }
      const unsigned* aw1 = (const unsigned*)&a1;
#pragma unroll
      for (int i = 0; i < 4; i++) { tmp[8+2*i] = (ushort)(aw1[i] & 0xffffu); tmp[8+2*i+1] = (ushort)(aw1[i] >> 16); }
    } else {            // fp32 source -> round to bf16
      const float* xp = (const float*)X + (size_t)c * NTOT + n0 + nq * 16;
#pragma unroll
      for (int k = 0; k < 4; k++) {
        float4 v = *(const float4*)(xp + 4 * k);
        tmp[4*k+0] = f2bf(v.x); tmp[4*k+1] = f2bf(v.y);
        tmp[4*k+2] = f2bf(v.z); tmp[4*k+3] = f2bf(v.w);
      }
    }
    ushort* dst = &xs[nq * 16][c];
#pragma unroll
    for (int i = 0; i < 16; i++) dst[i * 104] = tmp[i];
  }
  __syncthreads();
  const int wave = tid >> 6, lane = tid & 63;
  const int col = lane & 15, quad = lane >> 4;
  f32x4 acc[OF][4];
#pragma unroll
  for (int a = 0; a < OF; a++)
#pragma unroll
    for (int b = 0; b < 4; b++) acc[a][b] = (f32x4)0.f;
  const int obase = wave * (16 * OF);
#pragma unroll
  for (int ks = 0; ks < 3; ks++) {
    short8 bfrag[4];
#pragma unroll
    for (int nf = 0; nf < 4; nf++)
      bfrag[nf] = *(const short8*)&xs[nf*16 + col][ks*32 + quad*8];
#pragma unroll
    for (int of = 0; of < OF; of++) {
      const int o = obase + of*16 + col;  // A-row = lane&15
      short8 afrag = *(const short8*)(W + (size_t)o * 96 + ks*32 + quad*8);
#pragma unroll
      for (int nf = 0; nf < 4; nf++)
        acc[of][nf] = __builtin_amdgcn_mfma_f32_16x16x32_bf16(afrag, bfrag[nf], acc[of][nf], 0, 0, 0);
    }
  }
  // C/D layout: col = lane&15 (n), row = quad*4 + r (o)
#pragma unroll
  for (int of = 0; of < OF; of++)
#pragma unroll
    for (int nf = 0; nf < 4; nf++)
#pragma unroll
      for (int r = 0; r < 4; r++) {
        int o = obase + of*16 + quad*4 + r;
        long n = n0 + nf*16 + col;
        float v = acc[of][nf][r];
        if (!DYNOUT || f) ((ushort*)C)[(size_t)o * NTOT + n] = f2bf(v);
        else              ((float*) C)[(size_t)o * NTOT + n] = v;
      }
}

// depthwise 3x3x3, pad 1. block 256: dq(8) x wl(8) x hl(4); thread = 8 d-outputs.
// d-halo comes from neighbor lanes via shuffle (groups of 8 lanes share (h,w) row).
__global__ __launch_bounds__(256)
void dwconv3(const ushort* __restrict__ in, const void* __restrict__ wt,
             ushort* __restrict__ out, const int* __restrict__ flag) {
  const int c = blockIdx.z;
  const int tid = threadIdx.x;
  const int dq = tid & 7;
  const int w = blockIdx.y * 8 + ((tid >> 3) & 7);
  const int h = blockIdx.x * 4 + (tid >> 6);   // wave-uniform (wave = h)
  const int d0 = dq * 8;
  __shared__ float wsm[27];
  if (tid < 27) {
    int f = *flag;
    wsm[tid] = f ? bf2f(((const ushort*)wt)[c * 27 + tid])
                 : ((const float*)wt)[c * 27 + tid];
  }
  __syncthreads();
  float acc[8];
#pragma unroll
  for (int i = 0; i < 8; i++) acc[i] = 0.f;
  const size_t cbase = (size_t)c * NTOT;
#pragma unroll
  for (int dh = -1; dh <= 1; dh++) {
    int hh = h + dh;
    if (hh < 0 || hh > 63) continue;           // wave-uniform branch
#pragma unroll
    for (int dw = -1; dw <= 1; dw++) {
      int ww = w + dw;
      bool wok = (ww >= 0 && ww <= 63);        // uniform within each 8-lane group
      uint4 va = make_uint4(0u, 0u, 0u, 0u);
      if (wok)
        va = *(const uint4*)(in + cbase + ((size_t)hh * 64 + ww) * 64 + d0);
      const unsigned* u = (const unsigned*)&va;
      float x0 = bf2f((ushort)(u[0] & 0xffffu)), x1 = bf2f((ushort)(u[0] >> 16));
      float x2 = bf2f((ushort)(u[1] & 0xffffu)), x3 = bf2f((ushort)(u[1] >> 16));
      float x4 = bf2f((ushort)(u[2] & 0xffffu)), x5 = bf2f((ushort)(u[2] >> 16));
      float x6 = bf2f((ushort)(u[3] & 0xffffu)), x7 = bf2f((ushort)(u[3] >> 16));
      // d-halo via intra-wave shuffle within groups of 8 lanes (same (hh,ww) row)
      float xlm = __shfl_up(x7, 1, 8);
      float xrm = __shfl_down(x0, 1, 8);
      float xl = (dq > 0) ? xlm : 0.f;
      float xr = (dq < 7) ? xrm : 0.f;
      const int wb = (dh + 1) * 9 + (dw + 1) * 3;
      float wL = wsm[wb], wC = wsm[wb + 1], wR = wsm[wb + 2];
      acc[0] += wL*xl + wC*x0 + wR*x1;
      acc[1] += wL*x0 + wC*x1 + wR*x2;
      acc[2] += wL*x1 + wC*x2 + wR*x3;
      acc[3] += wL*x2 + wC*x3 + wR*x4;
      acc[4] += wL*x3 + wC*x4 + wR*x5;
      acc[5] += wL*x4 + wC*x5 + wR*x6;
      acc[6] += wL*x5 + wC*x6 + wR*x7;
      acc[7] += wL*x6 + wC*x7 + wR*xr;
    }
  }
  ushort o8[8];
#pragma unroll
  for (int i = 0; i < 8; i++) o8[i] = f2bf(acc[i]);
  *(uint4*)(out + cbase + ((size_t)h * 64 + w) * 64 + d0) = *(uint4*)o8;
}

// per-head Gram: G[hd][0]=q.kT, [1]=q.qT, [2]=k.kT  (each 16x16 fp32, atomic accum)
__global__ __launch_bounds__(256)
void gram16(const ushort* __restrict__ qk, float* __restrict__ G) {
  const int hd = blockIdx.y;
  const int tid = threadIdx.x, wave = tid >> 6, lane = tid & 63;
  const int col = lane & 15, quad = lane >> 4;
  const ushort* qp = qk + (size_t)(hd * 16 + col) * NTOT;
  const ushort* kp = qp + (size_t)96 * NTOT;
  f32x4 aqk = (f32x4)0.f, aqq = (f32x4)0.f, akk = (f32x4)0.f;
  const int nbase = blockIdx.x * 4096 + wave * 32 + quad * 8;
#pragma unroll 4
  for (int it = 0; it < 32; it++) {
    short8 qf = *(const short8*)(qp + nbase + it * 128);
    short8 kf = *(const short8*)(kp + nbase + it * 128);
    aqk = __builtin_amdgcn_mfma_f32_16x16x32_bf16(qf, kf, aqk, 0, 0, 0);
    aqq = __builtin_amdgcn_mfma_f32_16x16x32_bf16(qf, qf, aqq, 0, 0, 0);
    akk = __builtin_amdgcn_mfma_f32_16x16x32_bf16(kf, kf, akk, 0, 0, 0);
  }
  __shared__ float red[4][64][12];
#pragma unroll
  for (int r = 0; r < 4; r++) {
    red[wave][lane][r]     = aqk[r];
    red[wave][lane][4 + r] = aqq[r];
    red[wave][lane][8 + r] = akk[r];
  }
  __syncthreads();
  if (wave == 0) {
#pragma unroll
    for (int j = 0; j < 12; j++) {
      float v = red[0][lane][j] + red[1][lane][j] + red[2][lane][j] + red[3][lane][j];
      int sub = j >> 2, r = j & 3;
      atomicAdd(&G[hd * 768 + sub * 256 + (quad * 4 + r) * 16 + col], v);
    }
  }
}

// softmax over Gram + fold W_proj: M[o][hd*16+d] = sum_c wp[o][hd*16+c] * A[hd][c][d]
__global__ __launch_bounds__(256)
void attn_mix(const float* __restrict__ G, const void* __restrict__ wp,
              const void* __restrict__ temp, ushort* __restrict__ M,
              const int* __restrict__ flag) {
  __shared__ float As[6][16][16];
  const int tid = threadIdx.x;
  const int f = *flag;
  if (tid < 96) {
    int hd = tid >> 4, c = tid & 15;
    const float* Gh = G + hd * 768;
    float qn = fmaxf(sqrtf(fmaxf(Gh[256 + c * 17], 0.f)), 1e-12f);
    float t = f ? bf2f(((const ushort*)temp)[hd]) : ((const float*)temp)[hd];
    float lg[16];
    float mx = -1e30f;
#pragma unroll
    for (int d = 0; d < 16; d++) {
      float kn = fmaxf(sqrtf(fmaxf(Gh[512 + d * 17], 0.f)), 1e-12f);
      lg[d] = Gh[c * 16 + d] / (qn * kn) * t;
      mx = fmaxf(mx, lg[d]);
    }
    float s = 0.f;
#pragma unroll
    for (int d = 0; d < 16; d++) { lg[d] = __expf(lg[d] - mx); s += lg[d]; }
    float inv = 1.f / s;
#pragma unroll
    for (int d = 0; d < 16; d++) As[hd][c][d] = lg[d] * inv;
  }
  __syncthreads();
  for (int i = 0; i < 36; i++) {
    int idx = tid + 256 * i;           // 0..9215 covers 96*96
    int o = idx / 96, p = idx - o * 96;
    int hd = p >> 4, d = p & 15;
    float s = 0.f;
#pragma unroll
    for (int cc = 0; cc < 16; cc++) {
      float wv = f ? bf2f(((const ushort*)wp)[o * 96 + hd * 16 + cc])
                   : ((const float*)wp)[o * 96 + hd * 16 + cc];
      s += wv * As[hd][cc][d];
    }
    M[idx] = f2bf(s);
  }
}

extern "C" void kernel_launch(void* const* d_in, const int* in_sizes, int n_in,
                              void* d_out, int out_size, void* d_ws, size_t ws_size,
                              hipStream_t stream) {
  const void* x      = d_in[0];  // (96, 64,64,64)
  const void* w_qkv  = d_in[1];  // (288, 96)
  const void* w_dw   = d_in[2];  // (288, 27)
  const void* w_proj = d_in[3];  // (96, 96)
  const void* temp   = d_in[4];  // (6)

  const size_t szQKV = (size_t)288 * NTOT * 2;  // 151 MB
  ushort* B1 = (ushort*)d_ws;                                      // qkv after 1x1
  ushort* B2 = (ushort*)((char*)d_ws + szQKV);                     // qkv after dwconv
  char* tail = (char*)d_ws + 2 * szQKV;
  float*  G    = (float*)tail;                    // 6*768 fp32      (18432 B)
  ushort* M    = (ushort*)(tail + 18432);         // 96*96 bf16      (18432 B)
  ushort* Wb   = (ushort*)(tail + 36864);         // 288*96 bf16     (55296 B)
  int*    flag = (int*)(tail + 92160);
  if (ws_size < 2 * szQKV + 92160 + 256) return;  // fail loudly (zeros out)

  detect_dtype<<<1, 64, 0, stream>>>((const ushort*)w_qkv, flag);
  cvt_bf16<<<32, 256, 0, stream>>>(w_qkv, Wb, 288 * 96, flag);
  hipMemsetAsync(G, 0, 4608 * 4, stream);
  gemm96<3, true, false><<<4096, 384, 0, stream>>>(Wb, x, B1, flag);
  dwconv3<<<dim3(16, 8, 288), 256, 0, stream>>>(B1, w_dw, B2, flag);
  gram16<<<dim3(64, 6), 256, 0, stream>>>(B2, G);
  attn_mix<<<1, 256, 0, stream>>>(G, w_proj, temp, M, flag);
  gemm96<1, false, true><<<4096, 384, 0, stream>>>(M, B2 + (size_t)192 * NTOT, d_out, flag);
}

// Round 4
// 438.869 us; speedup vs baseline: 1.1956x; 1.0272x over previous
//
#include <hip/hip_runtime.h>
#include <hip/hip_bf16.h>
#include <hip/hip_fp16.h>

#define NTOT 262144  // 64*64*64 spatial
typedef __hip_bfloat16 bf16;
typedef __attribute__((ext_vector_type(4))) float f32x4;
typedef _Float16 f16x8 __attribute__((ext_vector_type(8)));

__device__ inline ushort f2bf(float f){ bf16 b = __float2bfloat16(f); return *(ushort*)&b; }
__device__ inline float bf2f(ushort u){ union{unsigned i;float f;}v; v.i = (unsigned)u<<16; return v.f; }
__device__ inline unsigned h2u(__half2 h){ union{__half2 h; unsigned u;}v; v.h=h; return v.u; }
__device__ inline __half2 u2h(unsigned u){ union{unsigned u; __half2 h;}v; v.u=u; return v.h; }
__device__ inline ushort f2h(float f){ __half h = __float2half_rn(f); return *(ushort*)&h; }

// ---- dtype detector: flag=1 if inputs are bf16, 0 if fp32 ----
__global__ void detect_dtype(const ushort* __restrict__ w, int* __restrict__ flag) {
  int tid = threadIdx.x;  // 64 threads
  int sane = 0;
  for (int i = tid; i < 512; i += 64) {
    ushort u = w[2 * i];
    int e = (u >> 7) & 0xff;
    sane += (e == 0 || (e >= 100 && e <= 140)) ? 1 : 0;
  }
#pragma unroll
  for (int off = 32; off > 0; off >>= 1) sane += __shfl_down(sane, off, 64);
  if (tid == 0) *flag = (sane >= 256) ? 1 : 0;
}

// convert small array (fp32 or bf16 per flag) to f16 bits
__global__ void cvt_f16(const void* __restrict__ in, ushort* __restrict__ outw,
                        int n, const int* __restrict__ flag) {
  int f = *flag;
  for (int i = blockIdx.x * 256 + threadIdx.x; i < n; i += gridDim.x * 256) {
    float v = f ? bf2f(((const ushort*)in)[i]) : ((const float*)in)[i];
    outw[i] = f2h(v);
  }
}

// transpose [96][NTOT] -> [NTOT][96] f16.  MODE 0: input f32/bf16 per flag; MODE 1: input f16.
template<int MODE>
__global__ __launch_bounds__(256)
void transpose96(const void* __restrict__ in, ushort* __restrict__ out,
                 const int* __restrict__ flag) {
  __shared__ float t[96][65];
  const int tid = threadIdx.x;
  const long n0 = (long)blockIdx.x * 64;
  const int f = (MODE == 0) ? *flag : 0;
#pragma unroll
  for (int i = 0; i < 6; i++) {
    int idx = tid + 256 * i;      // 0..1535
    int u = idx & 15, c = idx >> 4;
    float v0, v1, v2, v3;
    if (MODE == 0 && !f) {
      float4 q = *(const float4*)((const float*)in + (size_t)c * NTOT + n0 + u * 4);
      v0 = q.x; v1 = q.y; v2 = q.z; v3 = q.w;
    } else if (MODE == 0) {       // bf16 input
      uint2 q = *(const uint2*)((const ushort*)in + (size_t)c * NTOT + n0 + u * 4);
      v0 = bf2f((ushort)(q.x & 0xffffu)); v1 = bf2f((ushort)(q.x >> 16));
      v2 = bf2f((ushort)(q.y & 0xffffu)); v3 = bf2f((ushort)(q.y >> 16));
    } else {                      // f16 input
      uint2 q = *(const uint2*)((const ushort*)in + (size_t)c * NTOT + n0 + u * 4);
      __half2 a = u2h(q.x), b = u2h(q.y);
      v0 = __half2float(a.x); v1 = __half2float(a.y);
      v2 = __half2float(b.x); v3 = __half2float(b.y);
    }
    t[c][u*4+0] = v0; t[c][u*4+1] = v1; t[c][u*4+2] = v2; t[c][u*4+3] = v3;
  }
  __syncthreads();
#pragma unroll
  for (int i = 0; i < 3; i++) {
    int idx = tid + 256 * i;      // 0..767
    int oq = idx % 12, n = idx / 12;
    unsigned d[4];
#pragma unroll
    for (int j = 0; j < 4; j++) {
      __half2 hp = __floats2half2_rn(t[oq*8 + 2*j][n], t[oq*8 + 2*j + 1][n]);
      d[j] = h2u(hp);
    }
    *(uint4*)(out + (size_t)(n0 + n) * 96 + oq * 8) = make_uint4(d[0], d[1], d[2], d[3]);
  }
}

// C[o][n] = sum_c W[o][c] * Xt[n][c], K=96, O = 96*OF.  W k-major f16, Xt [n][96] f16.
// 384 threads = 6 waves; n-tile 64; no input LDS (direct-global fragments);
// epilogue staged in LDS for coalesced stores.
template<int OF, bool DYNOUT>
__global__ __launch_bounds__(384)
void gemm96f(const ushort* __restrict__ W, const ushort* __restrict__ Xt,
             void* __restrict__ C, const int* __restrict__ flag) {
  const int tid = threadIdx.x;
  const long n0 = (long)blockIdx.x * 64;
  const int wave = tid >> 6, lane = tid & 63;
  const int col = lane & 15, quad = lane >> 4;
  const int f = DYNOUT ? *flag : 0;
  f32x4 acc[OF][4];
#pragma unroll
  for (int a = 0; a < OF; a++)
#pragma unroll
    for (int b = 0; b < 4; b++) acc[a][b] = (f32x4)0.f;
  const int obase = wave * 16 * OF;
#pragma unroll
  for (int ks = 0; ks < 3; ks++) {
    f16x8 bfrag[4];
#pragma unroll
    for (int nf = 0; nf < 4; nf++)
      bfrag[nf] = *(const f16x8*)(Xt + (size_t)(n0 + nf*16 + col) * 96 + ks*32 + quad*8);
#pragma unroll
    for (int of = 0; of < OF; of++) {
      const int o = obase + of*16 + col;  // A-row = lane&15
      f16x8 afrag = *(const f16x8*)(W + (size_t)o * 96 + ks*32 + quad*8);
#pragma unroll
      for (int nf = 0; nf < 4; nf++)
        acc[of][nf] = __builtin_amdgcn_mfma_f32_16x16x32_f16(afrag, bfrag[nf], acc[of][nf], 0, 0, 0);
    }
  }
  // C/D layout: col = lane&15 (n), row = quad*4 + r (o). Stage in LDS, then coalesced store.
  __shared__ __align__(16) ushort cs[96 * OF][72];
#pragma unroll
  for (int of = 0; of < OF; of++)
#pragma unroll
    for (int nf = 0; nf < 4; nf++)
#pragma unroll
      for (int r = 0; r < 4; r++) {
        int o = obase + of*16 + quad*4 + r;
        cs[o][nf*16 + col] = f2h(acc[of][nf][r]);
      }
  __syncthreads();
  if (!DYNOUT) {
    // f16 out, 16B chunks: 768*OF uint4s, 384 threads -> 2*OF iters
#pragma unroll
    for (int i = 0; i < 2 * OF; i++) {
      int idx = tid + 384 * i;
      int o = idx >> 3, u = idx & 7;
      uint4 v = *(const uint4*)&cs[o][u * 8];
      *(uint4*)((ushort*)C + (size_t)o * NTOT + n0 + u * 8) = v;
    }
  } else {
    // 4-element chunks: 96*16 = 1536 / 384 = 4 iters
#pragma unroll
    for (int i = 0; i < 4; i++) {
      int idx = tid + 384 * i;
      int o = idx >> 4, u = idx & 15;
      uint2 v = *(const uint2*)&cs[o][u * 4];
      __half2 a = u2h(v.x), b = u2h(v.y);
      float f0 = __half2float(a.x), f1 = __half2float(a.y);
      float f2 = __half2float(b.x), f3 = __half2float(b.y);
      if (!f) {
        float4 q = {f0, f1, f2, f3};
        *(float4*)((float*)C + (size_t)o * NTOT + n0 + u * 4) = q;
      } else {
        uint2 q = make_uint2(((unsigned)f2bf(f1) << 16) | f2bf(f0),
                             ((unsigned)f2bf(f3) << 16) | f2bf(f2));
        *(uint2*)((ushort*)C + (size_t)o * NTOT + n0 + u * 4) = q;
      }
    }
  }
}

// depthwise 3x3x3, pad 1, f16 in/out, packed-f16 math.
// block 256: dq(8) x wl(8) x hl(4); thread = 8 d-outputs as 4 half2 accumulators.
__global__ __launch_bounds__(256)
void dwconv3(const ushort* __restrict__ in, const void* __restrict__ wt,
             ushort* __restrict__ out, const int* __restrict__ flag) {
  const int c = blockIdx.z;
  const int tid = threadIdx.x;
  const int dq = tid & 7;
  const int w = blockIdx.y * 8 + ((tid >> 3) & 7);
  const int h = blockIdx.x * 4 + (tid >> 6);   // wave-uniform
  const int d0 = dq * 8;
  __shared__ __half2 wsm2[27];
  if (tid < 27) {
    int f = *flag;
    float wv = f ? bf2f(((const ushort*)wt)[c * 27 + tid])
                 : ((const float*)wt)[c * 27 + tid];
    wsm2[tid] = __floats2half2_rn(wv, wv);
  }
  __syncthreads();
  const unsigned maskL = (dq == 0) ? 0xFFFF0000u : 0xFFFFFFFFu;  // zero x[-1]
  const unsigned maskR = (dq == 7) ? 0x0000FFFFu : 0xFFFFFFFFu;  // zero x[64]
  __half2 a0 = u2h(0), a1 = u2h(0), a2 = u2h(0), a3 = u2h(0);
  const size_t cbase = (size_t)c * NTOT;
#pragma unroll
  for (int dh = -1; dh <= 1; dh++) {
    int hh = h + dh;
    if (hh < 0 || hh > 63) continue;           // wave-uniform
#pragma unroll
    for (int dw = -1; dw <= 1; dw++) {
      int ww = w + dw;
      bool wok = (ww >= 0 && ww <= 63);        // uniform within 8-lane group
      uint4 u = make_uint4(0u, 0u, 0u, 0u);
      if (wok)
        u = *(const uint4*)(in + cbase + ((size_t)hh * 64 + ww) * 64 + d0);
      unsigned P = (unsigned)__shfl_up((int)u.w, 1, 8);     // prev lane {x6,x7}
      unsigned N = (unsigned)__shfl_down((int)u.x, 1, 8);   // next lane {x0,x1}
      // shifted pairs {x[2j-1], x[2j]} and tail {x7, x8}
      unsigned S0 = __builtin_amdgcn_perm(u.x, P,   0x05040302) & maskL; // {x-1,x0}
      unsigned S1 = __builtin_amdgcn_perm(u.y, u.x, 0x05040302);         // {x1,x2}
      unsigned S2 = __builtin_amdgcn_perm(u.z, u.y, 0x05040302);         // {x3,x4}
      unsigned S3 = __builtin_amdgcn_perm(u.w, u.z, 0x05040302);         // {x5,x6}
      unsigned R3 = __builtin_amdgcn_perm(N,   u.w, 0x05040302) & maskR; // {x7,x8}
      const int wb = (dh + 1) * 9 + (dw + 1) * 3;
      __half2 wL = wsm2[wb], wC = wsm2[wb + 1], wR = wsm2[wb + 2];
      a0 = __hfma2(wL, u2h(S0), a0); a0 = __hfma2(wC, u2h(u.x), a0); a0 = __hfma2(wR, u2h(S1), a0);
      a1 = __hfma2(wL, u2h(S1), a1); a1 = __hfma2(wC, u2h(u.y), a1); a1 = __hfma2(wR, u2h(S2), a1);
      a2 = __hfma2(wL, u2h(S2), a2); a2 = __hfma2(wC, u2h(u.z), a2); a2 = __hfma2(wR, u2h(S3), a2);
      a3 = __hfma2(wL, u2h(S3), a3); a3 = __hfma2(wC, u2h(u.w), a3); a3 = __hfma2(wR, u2h(R3), a3);
    }
  }
  *(uint4*)(out + cbase + ((size_t)h * 64 + w) * 64 + d0) =
      make_uint4(h2u(a0), h2u(a1), h2u(a2), h2u(a3));
}

// per-head Gram: G[hd][0]=q.kT, [1]=q.qT, [2]=k.kT  (each 16x16 fp32, atomic accum)
__global__ __launch_bounds__(256)
void gram16(const ushort* __restrict__ qk, float* __restrict__ G) {
  const int hd = blockIdx.y;
  const int tid = threadIdx.x, wave = tid >> 6, lane = tid & 63;
  const int col = lane & 15, quad = lane >> 4;
  const ushort* qp = qk + (size_t)(hd * 16 + col) * NTOT;
  const ushort* kp = qp + (size_t)96 * NTOT;
  f32x4 aqk = (f32x4)0.f, aqq = (f32x4)0.f, akk = (f32x4)0.f;
  const int nbase = blockIdx.x * 4096 + wave * 32 + quad * 8;
#pragma unroll 4
  for (int it = 0; it < 32; it++) {
    f16x8 qf = *(const f16x8*)(qp + nbase + it * 128);
    f16x8 kf = *(const f16x8*)(kp + nbase + it * 128);
    aqk = __builtin_amdgcn_mfma_f32_16x16x32_f16(qf, kf, aqk, 0, 0, 0);
    aqq = __builtin_amdgcn_mfma_f32_16x16x32_f16(qf, qf, aqq, 0, 0, 0);
    akk = __builtin_amdgcn_mfma_f32_16x16x32_f16(kf, kf, akk, 0, 0, 0);
  }
  __shared__ float red[4][64][12];
#pragma unroll
  for (int r = 0; r < 4; r++) {
    red[wave][lane][r]     = aqk[r];
    red[wave][lane][4 + r] = aqq[r];
    red[wave][lane][8 + r] = akk[r];
  }
  __syncthreads();
  if (wave == 0) {
#pragma unroll
    for (int j = 0; j < 12; j++) {
      float v = red[0][lane][j] + red[1][lane][j] + red[2][lane][j] + red[3][lane][j];
      int sub = j >> 2, r = j & 3;
      atomicAdd(&G[hd * 768 + sub * 256 + (quad * 4 + r) * 16 + col], v);
    }
  }
}

// softmax over Gram + fold W_proj: M[o][hd*16+d] = sum_c wp[o][hd*16+c] * A[hd][c][d]  (f16 out)
__global__ __launch_bounds__(256)
void attn_mix(const float* __restrict__ G, const void* __restrict__ wp,
              const void* __restrict__ temp, ushort* __restrict__ M,
              const int* __restrict__ flag) {
  __shared__ float As[6][16][16];
  const int tid = threadIdx.x;
  const int f = *flag;
  if (tid < 96) {
    int hd = tid >> 4, c = tid & 15;
    const float* Gh = G + hd * 768;
    float qn = fmaxf(sqrtf(fmaxf(Gh[256 + c * 17], 0.f)), 1e-12f);
    float t = f ? bf2f(((const ushort*)temp)[hd]) : ((const float*)temp)[hd];
    float lg[16];
    float mx = -1e30f;
#pragma unroll
    for (int d = 0; d < 16; d++) {
      float kn = fmaxf(sqrtf(fmaxf(Gh[512 + d * 17], 0.f)), 1e-12f);
      lg[d] = Gh[c * 16 + d] / (qn * kn) * t;
      mx = fmaxf(mx, lg[d]);
    }
    float s = 0.f;
#pragma unroll
    for (int d = 0; d < 16; d++) { lg[d] = __expf(lg[d] - mx); s += lg[d]; }
    float inv = 1.f / s;
#pragma unroll
    for (int d = 0; d < 16; d++) As[hd][c][d] = lg[d] * inv;
  }
  __syncthreads();
  for (int i = 0; i < 36; i++) {
    int idx = tid + 256 * i;           // 0..9215 covers 96*96
    int o = idx / 96, p = idx - o * 96;
    int hd = p >> 4, d = p & 15;
    float s = 0.f;
#pragma unroll
    for (int cc = 0; cc < 16; cc++) {
      float wv = f ? bf2f(((const ushort*)wp)[o * 96 + hd * 16 + cc])
                   : ((const float*)wp)[o * 96 + hd * 16 + cc];
      s += wv * As[hd][cc][d];
    }
    M[idx] = f2h(s);
  }
}

extern "C" void kernel_launch(void* const* d_in, const int* in_sizes, int n_in,
                              void* d_out, int out_size, void* d_ws, size_t ws_size,
                              hipStream_t stream) {
  const void* x      = d_in[0];  // (96, 64,64,64)
  const void* w_qkv  = d_in[1];  // (288, 96)
  const void* w_dw   = d_in[2];  // (288, 27)
  const void* w_proj = d_in[3];  // (96, 96)
  const void* temp   = d_in[4];  // (6)

  const size_t szQKV = (size_t)288 * NTOT * 2;  // 151 MB
  ushort* B1 = (ushort*)d_ws;                   // qkv after 1x1 (f16); later reused as Vt
  ushort* B2 = (ushort*)((char*)d_ws + szQKV);  // Xt first, then qkv after dwconv (f16)
  ushort* Xt = B2;                              // [NTOT][96] f16 (dead once dwconv writes B2)
  ushort* Vt = B1;                              // [NTOT][96] f16 (B1 dead after dwconv)
  char* tail = (char*)d_ws + 2 * szQKV;
  float*  G    = (float*)tail;                    // 6*768 fp32      (18432 B)
  ushort* M    = (ushort*)(tail + 18432);         // 96*96 f16
  ushort* Wh   = (ushort*)(tail + 36864);         // 288*96 f16      (55296 B)
  int*    flag = (int*)(tail + 92160);
  if (ws_size < 2 * szQKV + 92160 + 256) return;  // fail loudly (zeros out)

  detect_dtype<<<1, 64, 0, stream>>>((const ushort*)w_qkv, flag);
  cvt_f16<<<32, 256, 0, stream>>>(w_qkv, Wh, 288 * 96, flag);
  hipMemsetAsync(G, 0, 4608 * 4, stream);
  transpose96<0><<<4096, 256, 0, stream>>>(x, Xt, flag);
  gemm96f<3, false><<<4096, 384, 0, stream>>>(Wh, Xt, B1, flag);
  dwconv3<<<dim3(16, 8, 288), 256, 0, stream>>>(B1, w_dw, B2, flag);
  gram16<<<dim3(64, 6), 256, 0, stream>>>(B2, G);
  transpose96<1><<<4096, 256, 0, stream>>>(B2 + (size_t)192 * NTOT, Vt, flag);
  attn_mix<<<1, 256, 0, stream>>>(G, w_proj, temp, M, flag);
  gemm96f<1, true><<<4096, 384, 0, stream>>>(M, Vt, d_out, flag);
}